// Round 1
// baseline (137.787 us; speedup 1.0000x reference)
//
#include <hip/hip_runtime.h>

typedef unsigned long long ull;

#define TOKENS 2048
#define KNN    32
#define VOCAB  32000

// sorted-descending 8-element insert (static indices only)
#define INS(val, idx) do {                                                   \
    ull key_ = (((ull)__float_as_uint(val)) << 32) | (unsigned)(idx);        \
    if (key_ > t7) {                                                         \
        ull k_ = key_, tmp_;                                                 \
        if (k_ > t0) { tmp_ = t0; t0 = k_; k_ = tmp_; }                      \
        if (k_ > t1) { tmp_ = t1; t1 = k_; k_ = tmp_; }                      \
        if (k_ > t2) { tmp_ = t2; t2 = k_; k_ = tmp_; }                      \
        if (k_ > t3) { tmp_ = t3; t3 = k_; k_ = tmp_; }                      \
        if (k_ > t4) { tmp_ = t4; t4 = k_; k_ = tmp_; }                      \
        if (k_ > t5) { tmp_ = t5; t5 = k_; k_ = tmp_; }                      \
        if (k_ > t6) { tmp_ = t6; t6 = k_; k_ = tmp_; }                      \
        t7 = (k_ > t7) ? k_ : t7;                                            \
    }                                                                        \
} while (0)

__global__ __launch_bounds__(256, 4)
void rc_kernel(const int*   __restrict__ tgt_index,
               const float* __restrict__ knn_dists,
               const float* __restrict__ knn_key,
               const float* __restrict__ net_probs,
               const float* __restrict__ net_sel,
               const float* __restrict__ W_func, const float* __restrict__ b_func,
               const float* __restrict__ W1a,    const float* __restrict__ b1a,
               const float* __restrict__ W1b,    const float* __restrict__ b1b,
               const float* __restrict__ W2a,    const float* __restrict__ b2a,
               const float* __restrict__ W2b,    const float* __restrict__ b2b,
               float* __restrict__ out)
{
    const int t   = blockIdx.x;
    const int tid = threadIdx.x;

    __shared__ int   s_tgt[KNN];
    __shared__ float s_dist[KNN];
    __shared__ float s_cnt[KNN];
    __shared__ float s_top8[8];
    __shared__ ull   s_wmax[4];

    // ---- per-k loads (lanes 0..31) ----
    int   tg = 0;
    float d = 0.f, lk = 0.f, ls = 0.f;
    if (tid < KNN) {
        tg = tgt_index[t * KNN + tid];
        d  = knn_dists[t * KNN + tid];
        lk = logf(knn_key[t * KNN + tid]);
        ls = logf(net_sel[t * KNN + tid]);
        s_tgt[tid]  = tg;
        s_dist[tid] = d;
    }

    // ---- Phase 1: stream network_probs (top-8 scan) + zero the output row ----
    ull t0 = 0, t1 = 0, t2 = 0, t3 = 0, t4 = 0, t5 = 0, t6 = 0, t7 = 0;
    const float4* np4 = (const float4*)(net_probs + (size_t)t * VOCAB);
    float4*       o4  = (float4*)(out + (size_t)t * VOCAB);
    const float4  z4  = make_float4(0.f, 0.f, 0.f, 0.f);
    for (int i = tid; i < VOCAB / 4; i += 256) {
        float4 v = np4[i];
        o4[i] = z4;
        INS(v.x, 4 * i + 0);
        INS(v.y, 4 * i + 1);
        INS(v.z, 4 * i + 2);
        INS(v.w, 4 * i + 3);
    }
    __syncthreads();

    // ---- Phase 2: extract global top-8 (8 rounds of max-extraction) ----
    for (int r = 0; r < 8; ++r) {
        ull c = t0;                       // thread's current best (list sorted desc)
        #pragma unroll
        for (int off = 1; off < 64; off <<= 1) {
            ull o = __shfl_xor(c, off);
            if (o > c) c = o;
        }
        if ((tid & 63) == 0) s_wmax[tid >> 6] = c;
        __syncthreads();
        ull g = s_wmax[0];
        if (s_wmax[1] > g) g = s_wmax[1];
        if (s_wmax[2] > g) g = s_wmax[2];
        if (s_wmax[3] > g) g = s_wmax[3];
        if (t0 == g && g != 0ULL) {       // unique owner pops its head
            t0 = t1; t1 = t2; t2 = t3; t3 = t4; t4 = t5; t5 = t6; t6 = t7; t7 = 0;
        }
        if (tid == 0) s_top8[r] = __uint_as_float((unsigned)(g >> 32));
        __syncthreads();
    }

    // ---- Phase 3a: label counts (distinct, reference never counts label 0) ----
    if (tid < KNN) {
        int fo = (tg != 0) ? 1 : 0;
        if (fo) {
            for (int j = 0; j < tid; ++j)
                if (s_tgt[j] == tg) { fo = 0; break; }
        }
        int c = fo;
        #pragma unroll
        for (int off = 1; off < KNN; off <<= 1) {
            int n = __shfl_up(c, off, KNN);
            if (tid >= off) c += n;
        }
        s_cnt[tid] = (float)c;
    }
    __syncthreads();

    // ---- Phase 3b: tiny MLPs, softmaxes, scatter ----
    if (tid < KNN) {
        // noise_logit: Linear(2,4) -> tanh -> Linear(4,1)
        float noise = b1b[0];
        #pragma unroll
        for (int j = 0; j < 4; ++j) {
            float z = tanhf(W1a[2 * j] * lk + W1a[2 * j + 1] * ls + b1a[j]);
            noise += W1b[j] * z;
        }

        // sim_lambda = W_func . [log(top8) | log_key | log_sel] + b_func
        float sp = W_func[8 + tid] * lk + W_func[40 + tid] * ls;
        if (tid < 8) sp += W_func[tid] * logf(s_top8[tid]);
        #pragma unroll
        for (int off = 16; off; off >>= 1) sp += __shfl_xor(sp, off, KNN);
        float sim = sp + b_func[0];

        // lambda_logit: Linear(64,32) -> tanh -> Linear(32,2); lane = hidden unit
        float h = b2a[tid];
        const float* wr = W2a + tid * 64;
        #pragma unroll 8
        for (int i = 0; i < KNN; ++i) h += wr[i] * s_dist[i];
        #pragma unroll 8
        for (int i = 0; i < KNN; ++i) h += wr[KNN + i] * s_cnt[i];
        h = tanhf(h);
        float p0 = W2b[tid] * h;
        float p1 = W2b[KNN + tid] * h;
        #pragma unroll
        for (int off = 16; off; off >>= 1) {
            p0 += __shfl_xor(p0, off, KNN);
            p1 += __shfl_xor(p1, off, KNN);
        }
        float l0 = p0 + b2b[0];
        float l1 = p1 + b2b[1];

        float tempe = 1.f / (1.f + expf(-l1));          // sigmoid(l1)
        float lam   = 1.f / (1.f + expf(-(l0 - sim)));  // softmax([l0,sim])[0]

        // probs = softmax(-d*tempe + noise) over K
        float logit = -d * tempe + noise;
        float mx = logit;
        #pragma unroll
        for (int off = 16; off; off >>= 1) mx = fmaxf(mx, __shfl_xor(mx, off, KNN));
        float e = expf(logit - mx);
        float se = e;
        #pragma unroll
        for (int off = 16; off; off >>= 1) se += __shfl_xor(se, off, KNN);
        float p = e / se;

        // scatter, last-occurrence-wins on duplicate indices (numpy semantics)
        bool wrte = true;
        for (int j = tid + 1; j < KNN; ++j)
            if (s_tgt[j] == tg) { wrte = false; break; }
        if (wrte) out[(size_t)t * VOCAB + tg] = p;

        if (tid == 0) out[(size_t)TOKENS * VOCAB + t] = lam;
    }
}

extern "C" void kernel_launch(void* const* d_in, const int* in_sizes, int n_in,
                              void* d_out, int out_size, void* d_ws, size_t ws_size,
                              hipStream_t stream) {
    rc_kernel<<<TOKENS, 256, 0, stream>>>(
        (const int*)  d_in[0],   // tgt_index
        (const float*)d_in[1],   // knn_dists
        (const float*)d_in[2],   // knn_key_feature
        (const float*)d_in[3],   // network_probs
        (const float*)d_in[4],   // network_select_probs
        (const float*)d_in[5],  (const float*)d_in[6],   // W_func, b_func
        (const float*)d_in[7],  (const float*)d_in[8],   // W1a, b1a
        (const float*)d_in[9],  (const float*)d_in[10],  // W1b, b1b
        (const float*)d_in[11], (const float*)d_in[12],  // W2a, b2a
        (const float*)d_in[13], (const float*)d_in[14],  // W2b, b2b
        (float*)d_out);
}